// Round 9
// baseline (97.365 us; speedup 1.0000x reference)
//
#include <hip/hip_runtime.h>

#define HDIM 256
#define CSB  1024            // colsum blocks; pT is [HDIM][CSB] (1 MB)
#define RDB  1024            // rowdot blocks

// ---------------- Stage 0: zero the histogram ----------------
__global__ void k_zero(uint4* __restrict__ p, int n4) {
    int i = blockIdx.x * blockDim.x + threadIdx.x;
    if (i < n4) p[i] = make_uint4(0u, 0u, 0u, 0u);
}

// ---------------- Stage 1: histogram of src indices ----------------
__global__ void k_count(const int4* __restrict__ src4, const int* __restrict__ src,
                        int E, unsigned int* __restrict__ cnt) {
    int i = blockIdx.x * blockDim.x + threadIdx.x;
    int E4 = E >> 2;
    if (i < E4) {
        int4 v = src4[i];
        atomicAdd(&cnt[v.x], 1u); atomicAdd(&cnt[v.y], 1u);
        atomicAdd(&cnt[v.z], 1u); atomicAdd(&cnt[v.w], 1u);
    }
    if (i < (E & 3)) atomicAdd(&cnt[src[(E4 << 2) + i]], 1u);
}

// ---------------- Stage 2: weighted column sum, decoupled-prefetch pipeline ----------
// Wave w handles rows w, w+NW, ... Quad-unrolled: next quad's 8 loads issue into fresh
// temps BEFORE current quad's FMAs -> 4-8 rows (4-8KB) in flight per wave at all times.
__global__ __launch_bounds__(256)
void k_colsum(const float4* __restrict__ xs4, const unsigned int* __restrict__ cnt,
              int Ns, float* __restrict__ pT) {
    const int lane = threadIdx.x & 63;
    const int wv = blockIdx.x * 4 + (threadIdx.x >> 6);
    const int NW = CSB * 4;
    float4 acc = make_float4(0.f, 0.f, 0.f, 0.f);

    float c0 = 0.f, c1 = 0.f, c2 = 0.f, c3 = 0.f;
    float4 x0 = make_float4(0,0,0,0), x1 = x0, x2 = x0, x3 = x0;
    int r = wv;
    // prologue (guarded; OOB slots stay zero)
    if (r          < Ns) { c0 = (float)cnt[r];          x0 = xs4[(size_t)r * 64 + lane]; }
    if (r + NW     < Ns) { c1 = (float)cnt[r + NW];     x1 = xs4[(size_t)(r + NW) * 64 + lane]; }
    if (r + 2 * NW < Ns) { c2 = (float)cnt[r + 2 * NW]; x2 = xs4[(size_t)(r + 2 * NW) * 64 + lane]; }
    if (r + 3 * NW < Ns) { c3 = (float)cnt[r + 3 * NW]; x3 = xs4[(size_t)(r + 3 * NW) * 64 + lane]; }

    // steady: prefetch next quad (unguarded), consume current, rotate
    for (; r + 7 * NW < Ns; r += 4 * NW) {
        const int p = r + 4 * NW;
        float  nc0 = (float)cnt[p];           float4 nx0 = xs4[(size_t)p * 64 + lane];
        float  nc1 = (float)cnt[p + NW];      float4 nx1 = xs4[(size_t)(p + NW) * 64 + lane];
        float  nc2 = (float)cnt[p + 2 * NW];  float4 nx2 = xs4[(size_t)(p + 2 * NW) * 64 + lane];
        float  nc3 = (float)cnt[p + 3 * NW];  float4 nx3 = xs4[(size_t)(p + 3 * NW) * 64 + lane];
        acc.x += c0 * x0.x; acc.y += c0 * x0.y; acc.z += c0 * x0.z; acc.w += c0 * x0.w;
        acc.x += c1 * x1.x; acc.y += c1 * x1.y; acc.z += c1 * x1.z; acc.w += c1 * x1.w;
        acc.x += c2 * x2.x; acc.y += c2 * x2.y; acc.z += c2 * x2.z; acc.w += c2 * x2.w;
        acc.x += c3 * x3.x; acc.y += c3 * x3.y; acc.z += c3 * x3.z; acc.w += c3 * x3.w;
        c0 = nc0; x0 = nx0; c1 = nc1; x1 = nx1;
        c2 = nc2; x2 = nx2; c3 = nc3; x3 = nx3;
    }
    // drain current quad (OOB slots have c=0)
    acc.x += c0 * x0.x; acc.y += c0 * x0.y; acc.z += c0 * x0.z; acc.w += c0 * x0.w;
    acc.x += c1 * x1.x; acc.y += c1 * x1.y; acc.z += c1 * x1.z; acc.w += c1 * x1.w;
    acc.x += c2 * x2.x; acc.y += c2 * x2.y; acc.z += c2 * x2.z; acc.w += c2 * x2.w;
    acc.x += c3 * x3.x; acc.y += c3 * x3.y; acc.z += c3 * x3.z; acc.w += c3 * x3.w;
    // tail singles (at most 3)
    for (int s = r + 4 * NW; s < Ns; s += NW) {
        float  cc = (float)cnt[s];
        float4 xx = xs4[(size_t)s * 64 + lane];
        acc.x += cc * xx.x; acc.y += cc * xx.y; acc.z += cc * xx.z; acc.w += cc * xx.w;
    }

    __shared__ float s[4 * HDIM];
    const int col = lane * 4;
    const int rowOff = threadIdx.x >> 6;
    s[rowOff * HDIM + col + 0] = acc.x;
    s[rowOff * HDIM + col + 1] = acc.y;
    s[rowOff * HDIM + col + 2] = acc.z;
    s[rowOff * HDIM + col + 3] = acc.w;
    __syncthreads();
    const int tid = threadIdx.x;
    float part = (s[tid] + s[HDIM + tid]) + (s[2 * HDIM + tid] + s[3 * HDIM + tid]);
    pT[(size_t)tid * CSB + blockIdx.x] = part;
}

// ---------------- Stage 3 (fused): ls = rowsum(pT); v = R @ ls --------------------
// One block, 1024 threads = (h = tid>>2, q = tid&3). 8-deep batched float4 loads:
// 1MB pT in ~8 latency rounds (~2.5us) instead of a serial chain.
__global__ __launch_bounds__(1024)
void k_reduce_mv(const float4* __restrict__ pT4, const float* __restrict__ Rm,
                 float* __restrict__ v) {
    const int tid = threadIdx.x;
    const int h = tid >> 2;
    const int q = tid & 3;
    __shared__ float red[4][HDIM];
    __shared__ float lss[HDIM];

    const float4* row = pT4 + (size_t)h * (CSB / 4) + q * (CSB / 16);
    float4 s4 = make_float4(0.f, 0.f, 0.f, 0.f);
    #pragma unroll
    for (int i0 = 0; i0 < CSB / 16; i0 += 8) {
        float4 t0 = row[i0 + 0], t1 = row[i0 + 1], t2 = row[i0 + 2], t3 = row[i0 + 3];
        float4 t4 = row[i0 + 4], t5 = row[i0 + 5], t6 = row[i0 + 6], t7 = row[i0 + 7];
        s4.x += t0.x + t4.x; s4.y += t0.y + t4.y; s4.z += t0.z + t4.z; s4.w += t0.w + t4.w;
        s4.x += t1.x + t5.x; s4.y += t1.y + t5.y; s4.z += t1.z + t5.z; s4.w += t1.w + t5.w;
        s4.x += t2.x + t6.x; s4.y += t2.y + t6.y; s4.z += t2.z + t6.z; s4.w += t2.w + t6.w;
        s4.x += t3.x + t7.x; s4.y += t3.y + t7.y; s4.z += t3.z + t7.z; s4.w += t3.w + t7.w;
    }
    red[q][h] = (s4.x + s4.y) + (s4.z + s4.w);
    __syncthreads();
    if (tid < HDIM) lss[tid] = (red[0][tid] + red[1][tid]) + (red[2][tid] + red[3][tid]);
    __syncthreads();

    // matvec: thread (h,q) does a 64-element slice of row h
    const float4* R4 = (const float4*)Rm + (size_t)h * 64 + q * 16;
    float m = 0.f;
    #pragma unroll
    for (int j = 0; j < 16; ++j) {
        float4 rr = R4[j];
        const int b = q * 64 + j * 4;
        m += rr.x * lss[b] + rr.y * lss[b + 1] + rr.z * lss[b + 2] + rr.w * lss[b + 3];
    }
    red[q][h] = m;
    __syncthreads();
    if (tid < HDIM) v[tid] = (red[0][tid] + red[1][tid]) + (red[2][tid] + red[3][tid]);
}

// ---------------- Stage 4: t[n] = x_trg[n] . v, same decoupled pipeline ------------
__global__ __launch_bounds__(256)
void k_rowdot(const float4* __restrict__ xt4, const float* __restrict__ v,
              int N, float* __restrict__ t) {
    const int lane = threadIdx.x & 63;
    const float4 vr = ((const float4*)v)[lane];
    const int wv = blockIdx.x * 4 + (threadIdx.x >> 6);
    const int NW = RDB * 4;

    float4 x0 = make_float4(0,0,0,0), x1 = x0, x2 = x0, x3 = x0;
    int r = wv;
    if (r          < N) x0 = xt4[(size_t)r * 64 + lane];
    if (r + NW     < N) x1 = xt4[(size_t)(r + NW) * 64 + lane];
    if (r + 2 * NW < N) x2 = xt4[(size_t)(r + 2 * NW) * 64 + lane];
    if (r + 3 * NW < N) x3 = xt4[(size_t)(r + 3 * NW) * 64 + lane];

#define RD_DOT(X) ((X).x * vr.x + (X).y * vr.y + (X).z * vr.z + (X).w * vr.w)
    for (; r + 7 * NW < N; r += 4 * NW) {
        const int p = r + 4 * NW;
        float4 nx0 = xt4[(size_t)p * 64 + lane];
        float4 nx1 = xt4[(size_t)(p + NW) * 64 + lane];
        float4 nx2 = xt4[(size_t)(p + 2 * NW) * 64 + lane];
        float4 nx3 = xt4[(size_t)(p + 3 * NW) * 64 + lane];
        float d0 = RD_DOT(x0), d1 = RD_DOT(x1), d2 = RD_DOT(x2), d3 = RD_DOT(x3);
        #pragma unroll
        for (int o = 32; o > 0; o >>= 1) {
            d0 += __shfl_down(d0, o, 64); d1 += __shfl_down(d1, o, 64);
            d2 += __shfl_down(d2, o, 64); d3 += __shfl_down(d3, o, 64);
        }
        if (lane == 0) { t[r] = d0; t[r + NW] = d1; t[r + 2 * NW] = d2; t[r + 3 * NW] = d3; }
        x0 = nx0; x1 = nx1; x2 = nx2; x3 = nx3;
    }
    // drain (guarded stores)
    {
        float d0 = RD_DOT(x0), d1 = RD_DOT(x1), d2 = RD_DOT(x2), d3 = RD_DOT(x3);
        #pragma unroll
        for (int o = 32; o > 0; o >>= 1) {
            d0 += __shfl_down(d0, o, 64); d1 += __shfl_down(d1, o, 64);
            d2 += __shfl_down(d2, o, 64); d3 += __shfl_down(d3, o, 64);
        }
        if (lane == 0) {
            if (r          < N) t[r]          = d0;
            if (r + NW     < N) t[r + NW]     = d1;
            if (r + 2 * NW < N) t[r + 2 * NW] = d2;
            if (r + 3 * NW < N) t[r + 3 * NW] = d3;
        }
    }
    // tail singles
    for (int s = r + 4 * NW; s < N; s += NW) {
        float4 xx = xt4[(size_t)s * 64 + lane];
        float d = RD_DOT(xx);
        #pragma unroll
        for (int o = 32; o > 0; o >>= 1) d += __shfl_down(d, o, 64);
        if (lane == 0) t[s] = d;
    }
#undef RD_DOT
}

// ---------------- Stage 5: out[e] = t[trg[e]] (vectorized gather) ----------------
__global__ void k_gather(const int4* __restrict__ trg4, const int* __restrict__ trg, int E,
                         const float* __restrict__ t,
                         float4* __restrict__ out4, float* __restrict__ out) {
    int i = blockIdx.x * blockDim.x + threadIdx.x;
    int E4 = E >> 2;
    if (i < E4) {
        int4 v = trg4[i];
        out4[i] = make_float4(t[v.x], t[v.y], t[v.z], t[v.w]);
    }
    if (i < (E & 3)) {
        int e = (E4 << 2) + i;
        out[e] = t[trg[e]];
    }
}

extern "C" void kernel_launch(void* const* d_in, const int* in_sizes, int n_in,
                              void* d_out, int out_size, void* d_ws, size_t ws_size,
                              hipStream_t stream) {
    const float* x_src = (const float*)d_in[0];
    const float* x_trg = (const float*)d_in[1];
    const float* Rm    = (const float*)d_in[2];
    const int*   edge  = (const int*)d_in[3];   // [0..E)=src, [E..2E)=trg
    float* out = (float*)d_out;

    const int Ns = in_sizes[0] / HDIM;
    const int Nt = in_sizes[1] / HDIM;
    const int E  = in_sizes[3] / 2;

    // Workspace carve-out (256B-aligned slices).
    char* ws = (char*)d_ws;
    size_t off = 0;
    auto alloc = [&](size_t bytes) -> void* {
        void* p = ws + off;
        off = (off + bytes + 255) & ~(size_t)255;
        return p;
    };
    unsigned int* cnt = (unsigned int*)alloc((size_t)Ns * sizeof(unsigned int)); // 200KB
    float* pT = (float*)alloc((size_t)HDIM * CSB * sizeof(float));               // 1MB
    float* v  = (float*)alloc(HDIM * sizeof(float));
    float* t  = (float*)alloc((size_t)Nt * sizeof(float));
    (void)ws_size; (void)n_in; (void)out_size;

    const int n4 = (Ns + 3) / 4;
    k_zero<<<(n4 + 255) / 256, 256, 0, stream>>>((uint4*)cnt, n4);

    const int E4 = E >> 2;
    const int cntThreads = (E4 > 0 ? E4 : 1);
    k_count<<<(cntThreads + 255) / 256, 256, 0, stream>>>(
        (const int4*)edge, edge, E, cnt);

    k_colsum<<<CSB, 256, 0, stream>>>((const float4*)x_src, cnt, Ns, pT);

    k_reduce_mv<<<1, 1024, 0, stream>>>((const float4*)pT, Rm, v);

    k_rowdot<<<RDB, 256, 0, stream>>>((const float4*)x_trg, v, Nt, t);

    k_gather<<<(cntThreads + 255) / 256, 256, 0, stream>>>(
        (const int4*)(edge + E), edge + E, E, t, (float4*)out, out);
}

// Round 10
// 54.096 us; speedup vs baseline: 1.7998x; 1.7998x over previous
//
#include <hip/hip_runtime.h>

#define HDIM 256
#define CSB  1024            // colsum blocks; pT is [HDIM][CSB] (1 MB)
#define RDB  1024            // rowdot blocks

// ---------------- Stage 0: zero the histogram ----------------
__global__ void k_zero(uint4* __restrict__ p, int n4) {
    int i = blockIdx.x * blockDim.x + threadIdx.x;
    if (i < n4) p[i] = make_uint4(0u, 0u, 0u, 0u);
}

// ---------------- Stage 1: histogram of src indices ----------------
__global__ void k_count(const int4* __restrict__ src4, const int* __restrict__ src,
                        int E, unsigned int* __restrict__ cnt) {
    int i = blockIdx.x * blockDim.x + threadIdx.x;
    int E4 = E >> 2;
    if (i < E4) {
        int4 v = src4[i];
        atomicAdd(&cnt[v.x], 1u); atomicAdd(&cnt[v.y], 1u);
        atomicAdd(&cnt[v.z], 1u); atomicAdd(&cnt[v.w], 1u);
    }
    if (i < (E & 3)) atomicAdd(&cnt[src[(E4 << 2) + i]], 1u);
}

// ---------------- Stage 2: weighted column sum, decoupled-prefetch pipeline ----------
// (round 9: this + rowdot's pipeline gained ~12us vs guarded-unroll -- keep.)
__global__ __launch_bounds__(256)
void k_colsum(const float4* __restrict__ xs4, const unsigned int* __restrict__ cnt,
              int Ns, float* __restrict__ pT) {
    const int lane = threadIdx.x & 63;
    const int wv = blockIdx.x * 4 + (threadIdx.x >> 6);
    const int NW = CSB * 4;
    float4 acc = make_float4(0.f, 0.f, 0.f, 0.f);

    float c0 = 0.f, c1 = 0.f, c2 = 0.f, c3 = 0.f;
    float4 x0 = make_float4(0,0,0,0), x1 = x0, x2 = x0, x3 = x0;
    int r = wv;
    if (r          < Ns) { c0 = (float)cnt[r];          x0 = xs4[(size_t)r * 64 + lane]; }
    if (r + NW     < Ns) { c1 = (float)cnt[r + NW];     x1 = xs4[(size_t)(r + NW) * 64 + lane]; }
    if (r + 2 * NW < Ns) { c2 = (float)cnt[r + 2 * NW]; x2 = xs4[(size_t)(r + 2 * NW) * 64 + lane]; }
    if (r + 3 * NW < Ns) { c3 = (float)cnt[r + 3 * NW]; x3 = xs4[(size_t)(r + 3 * NW) * 64 + lane]; }

    for (; r + 7 * NW < Ns; r += 4 * NW) {
        const int p = r + 4 * NW;
        float  nc0 = (float)cnt[p];           float4 nx0 = xs4[(size_t)p * 64 + lane];
        float  nc1 = (float)cnt[p + NW];      float4 nx1 = xs4[(size_t)(p + NW) * 64 + lane];
        float  nc2 = (float)cnt[p + 2 * NW];  float4 nx2 = xs4[(size_t)(p + 2 * NW) * 64 + lane];
        float  nc3 = (float)cnt[p + 3 * NW];  float4 nx3 = xs4[(size_t)(p + 3 * NW) * 64 + lane];
        acc.x += c0 * x0.x; acc.y += c0 * x0.y; acc.z += c0 * x0.z; acc.w += c0 * x0.w;
        acc.x += c1 * x1.x; acc.y += c1 * x1.y; acc.z += c1 * x1.z; acc.w += c1 * x1.w;
        acc.x += c2 * x2.x; acc.y += c2 * x2.y; acc.z += c2 * x2.z; acc.w += c2 * x2.w;
        acc.x += c3 * x3.x; acc.y += c3 * x3.y; acc.z += c3 * x3.z; acc.w += c3 * x3.w;
        c0 = nc0; x0 = nx0; c1 = nc1; x1 = nx1;
        c2 = nc2; x2 = nx2; c3 = nc3; x3 = nx3;
    }
    acc.x += c0 * x0.x; acc.y += c0 * x0.y; acc.z += c0 * x0.z; acc.w += c0 * x0.w;
    acc.x += c1 * x1.x; acc.y += c1 * x1.y; acc.z += c1 * x1.z; acc.w += c1 * x1.w;
    acc.x += c2 * x2.x; acc.y += c2 * x2.y; acc.z += c2 * x2.z; acc.w += c2 * x2.w;
    acc.x += c3 * x3.x; acc.y += c3 * x3.y; acc.z += c3 * x3.z; acc.w += c3 * x3.w;
    for (int s = r + 4 * NW; s < Ns; s += NW) {
        float  cc = (float)cnt[s];
        float4 xx = xs4[(size_t)s * 64 + lane];
        acc.x += cc * xx.x; acc.y += cc * xx.y; acc.z += cc * xx.z; acc.w += cc * xx.w;
    }

    __shared__ float s[4 * HDIM];
    const int col = lane * 4;
    const int rowOff = threadIdx.x >> 6;
    s[rowOff * HDIM + col + 0] = acc.x;
    s[rowOff * HDIM + col + 1] = acc.y;
    s[rowOff * HDIM + col + 2] = acc.z;
    s[rowOff * HDIM + col + 3] = acc.w;
    __syncthreads();
    const int tid = threadIdx.x;
    float part = (s[tid] + s[HDIM + tid]) + (s[2 * HDIM + tid] + s[3 * HDIM + tid]);
    pT[(size_t)tid * CSB + blockIdx.x] = part;
}

// ---------------- Stage 3: ls[h] = sum_b pT[h][b] ----------------
// 256 blocks; block h reads its contiguous 4KB row, coalesced. (round-9 lesson:
// the fused single-block version had lanes 1KB apart = 64 transactions/load = 52us.)
__global__ __launch_bounds__(256)
void k_reduceT(const float* __restrict__ pT, float* __restrict__ ls) {
    const int h = blockIdx.x;
    const int tid = threadIdx.x;
    const float* row = pT + (size_t)h * CSB;
    float a = (row[tid] + row[tid + 256]) + (row[tid + 512] + row[tid + 768]);
    #pragma unroll
    for (int o = 32; o > 0; o >>= 1) a += __shfl_down(a, o, 64);
    __shared__ float s[4];
    if ((tid & 63) == 0) s[tid >> 6] = a;
    __syncthreads();
    if (tid == 0) ls[h] = (s[0] + s[1]) + (s[2] + s[3]);
}

// ---------------- Stage 4: v[i] = R[i,:] . ls  (256 blocks, coalesced R read) ------
__global__ __launch_bounds__(256)
void k_matvec(const float* __restrict__ Rm, const float* __restrict__ ls,
              float* __restrict__ v) {
    const int i = blockIdx.x;
    const int tid = threadIdx.x;
    float a = Rm[(size_t)i * HDIM + tid] * ls[tid];   // lane-consecutive -> coalesced
    #pragma unroll
    for (int o = 32; o > 0; o >>= 1) a += __shfl_down(a, o, 64);
    __shared__ float s[4];
    if ((tid & 63) == 0) s[tid >> 6] = a;
    __syncthreads();
    if (tid == 0) v[i] = (s[0] + s[1]) + (s[2] + s[3]);
}

// ---------------- Stage 5: t[n] = x_trg[n] . v, decoupled pipeline ------------
__global__ __launch_bounds__(256)
void k_rowdot(const float4* __restrict__ xt4, const float* __restrict__ v,
              int N, float* __restrict__ t) {
    const int lane = threadIdx.x & 63;
    const float4 vr = ((const float4*)v)[lane];
    const int wv = blockIdx.x * 4 + (threadIdx.x >> 6);
    const int NW = RDB * 4;

    float4 x0 = make_float4(0,0,0,0), x1 = x0, x2 = x0, x3 = x0;
    int r = wv;
    if (r          < N) x0 = xt4[(size_t)r * 64 + lane];
    if (r + NW     < N) x1 = xt4[(size_t)(r + NW) * 64 + lane];
    if (r + 2 * NW < N) x2 = xt4[(size_t)(r + 2 * NW) * 64 + lane];
    if (r + 3 * NW < N) x3 = xt4[(size_t)(r + 3 * NW) * 64 + lane];

#define RD_DOT(X) ((X).x * vr.x + (X).y * vr.y + (X).z * vr.z + (X).w * vr.w)
    for (; r + 7 * NW < N; r += 4 * NW) {
        const int p = r + 4 * NW;
        float4 nx0 = xt4[(size_t)p * 64 + lane];
        float4 nx1 = xt4[(size_t)(p + NW) * 64 + lane];
        float4 nx2 = xt4[(size_t)(p + 2 * NW) * 64 + lane];
        float4 nx3 = xt4[(size_t)(p + 3 * NW) * 64 + lane];
        float d0 = RD_DOT(x0), d1 = RD_DOT(x1), d2 = RD_DOT(x2), d3 = RD_DOT(x3);
        #pragma unroll
        for (int o = 32; o > 0; o >>= 1) {
            d0 += __shfl_down(d0, o, 64); d1 += __shfl_down(d1, o, 64);
            d2 += __shfl_down(d2, o, 64); d3 += __shfl_down(d3, o, 64);
        }
        if (lane == 0) { t[r] = d0; t[r + NW] = d1; t[r + 2 * NW] = d2; t[r + 3 * NW] = d3; }
        x0 = nx0; x1 = nx1; x2 = nx2; x3 = nx3;
    }
    {
        float d0 = RD_DOT(x0), d1 = RD_DOT(x1), d2 = RD_DOT(x2), d3 = RD_DOT(x3);
        #pragma unroll
        for (int o = 32; o > 0; o >>= 1) {
            d0 += __shfl_down(d0, o, 64); d1 += __shfl_down(d1, o, 64);
            d2 += __shfl_down(d2, o, 64); d3 += __shfl_down(d3, o, 64);
        }
        if (lane == 0) {
            if (r          < N) t[r]          = d0;
            if (r + NW     < N) t[r + NW]     = d1;
            if (r + 2 * NW < N) t[r + 2 * NW] = d2;
            if (r + 3 * NW < N) t[r + 3 * NW] = d3;
        }
    }
    for (int s = r + 4 * NW; s < N; s += NW) {
        float4 xx = xt4[(size_t)s * 64 + lane];
        float d = RD_DOT(xx);
        #pragma unroll
        for (int o = 32; o > 0; o >>= 1) d += __shfl_down(d, o, 64);
        if (lane == 0) t[s] = d;
    }
#undef RD_DOT
}

// ---------------- Stage 6: out[e] = t[trg[e]] (vectorized gather) ----------------
__global__ void k_gather(const int4* __restrict__ trg4, const int* __restrict__ trg, int E,
                         const float* __restrict__ t,
                         float4* __restrict__ out4, float* __restrict__ out) {
    int i = blockIdx.x * blockDim.x + threadIdx.x;
    int E4 = E >> 2;
    if (i < E4) {
        int4 v = trg4[i];
        out4[i] = make_float4(t[v.x], t[v.y], t[v.z], t[v.w]);
    }
    if (i < (E & 3)) {
        int e = (E4 << 2) + i;
        out[e] = t[trg[e]];
    }
}

extern "C" void kernel_launch(void* const* d_in, const int* in_sizes, int n_in,
                              void* d_out, int out_size, void* d_ws, size_t ws_size,
                              hipStream_t stream) {
    const float* x_src = (const float*)d_in[0];
    const float* x_trg = (const float*)d_in[1];
    const float* Rm    = (const float*)d_in[2];
    const int*   edge  = (const int*)d_in[3];   // [0..E)=src, [E..2E)=trg
    float* out = (float*)d_out;

    const int Ns = in_sizes[0] / HDIM;
    const int Nt = in_sizes[1] / HDIM;
    const int E  = in_sizes[3] / 2;

    // Workspace carve-out (256B-aligned slices).
    char* ws = (char*)d_ws;
    size_t off = 0;
    auto alloc = [&](size_t bytes) -> void* {
        void* p = ws + off;
        off = (off + bytes + 255) & ~(size_t)255;
        return p;
    };
    unsigned int* cnt = (unsigned int*)alloc((size_t)Ns * sizeof(unsigned int)); // 200KB
    float* pT = (float*)alloc((size_t)HDIM * CSB * sizeof(float));               // 1MB
    float* ls = (float*)alloc(HDIM * sizeof(float));
    float* v  = (float*)alloc(HDIM * sizeof(float));
    float* t  = (float*)alloc((size_t)Nt * sizeof(float));
    (void)ws_size; (void)n_in; (void)out_size;

    const int n4 = (Ns + 3) / 4;
    k_zero<<<(n4 + 255) / 256, 256, 0, stream>>>((uint4*)cnt, n4);

    const int E4 = E >> 2;
    const int cntThreads = (E4 > 0 ? E4 : 1);
    k_count<<<(cntThreads + 255) / 256, 256, 0, stream>>>(
        (const int4*)edge, edge, E, cnt);

    k_colsum<<<CSB, 256, 0, stream>>>((const float4*)x_src, cnt, Ns, pT);

    k_reduceT<<<HDIM, 256, 0, stream>>>(pT, ls);

    k_matvec<<<HDIM, 256, 0, stream>>>(Rm, ls, v);

    k_rowdot<<<RDB, 256, 0, stream>>>((const float4*)x_trg, v, Nt, t);

    k_gather<<<(cntThreads + 255) / 256, 256, 0, stream>>>(
        (const int4*)(edge + E), edge + E, E, t, (float4*)out, out);
}